// Round 1
// baseline (342.660 us; speedup 1.0000x reference)
//
#include <hip/hip_runtime.h>
#include <cstdint>

#define TTOK 16384
#define HD   1024
#define NE   8
#define NDE  128
#define NDS  512
#define NC1  1536   // fc1 output cols = E*DE + DS
#define KC2  1536   // fc2 K

typedef float  f32x4  __attribute__((ext_vector_type(4)));
typedef __bf16 bf16x8 __attribute__((ext_vector_type(8)));

__device__ __forceinline__ unsigned short f2bf(float f) {
  unsigned int u = __float_as_uint(f);
  u += 0x7fffu + ((u >> 16) & 1u);   // RNE; inputs finite
  return (unsigned short)(u >> 16);
}

__device__ __forceinline__ void gl2lds16(const void* gp, void* lp) {
  void* g0 = const_cast<void*>(gp);
  __builtin_amdgcn_global_load_lds((__attribute__((address_space(1))) void*)g0,
                                   (__attribute__((address_space(3))) void*)lp,
                                   16, 0, 0);
}

// ---------------- prep: pack weights into bf16 concatenated layouts ----------------
__global__ void prep_kernel(const float* __restrict__ W1, const float* __restrict__ Ws1,
                            const float* __restrict__ W2, const float* __restrict__ Ws2,
                            const float* __restrict__ b1, const float* __restrict__ bs1,
                            unsigned short* __restrict__ W1cat,
                            unsigned short* __restrict__ W2cat,
                            float* __restrict__ bias1) {
  const int total = NC1 * HD + HD * KC2 + NC1;
  for (int idx = blockIdx.x * 256 + threadIdx.x; idx < total; idx += gridDim.x * 256) {
    if (idx < NC1 * HD) {
      // W1cat[r][k], r<1024: W1 flat [E*DE, H]; r>=1024: Ws1[r-1024]
      int r = idx >> 10, k = idx & 1023;
      float v = (r < 1024) ? W1[idx] : Ws1[(size_t)(r - 1024) * HD + k];
      W1cat[idx] = f2bf(v);
    } else if (idx < NC1 * HD + HD * KC2) {
      // W2cat[h][j], j<1024: W2[e=j>>7, h, f=j&127]; j>=1024: Ws2[h][j-1024]
      int i2 = idx - NC1 * HD;
      int h = i2 / KC2;
      int j = i2 - h * KC2;
      float v = (j < 1024) ? W2[(size_t)((j >> 7) * HD + h) * NDE + (j & 127)]
                           : Ws2[(size_t)h * NDS + (j - 1024)];
      W2cat[i2] = f2bf(v);
    } else {
      int r = idx - (NC1 * HD + HD * KC2);
      bias1[r] = (r < 1024) ? b1[r] : bs1[r - 1024];
    }
  }
}

// ---------------- gate: logits fp32, softmax, top-2, w[T,8]; also x -> bf16 ----------------
__global__ __launch_bounds__(256) void gate_kernel(const float* __restrict__ x,
                                                   const float* __restrict__ Wg,
                                                   unsigned short* __restrict__ xbf,
                                                   float* __restrict__ wgt) {
  const int lane = threadIdx.x & 63;
  const int wv   = threadIdx.x >> 6;
  const int t    = blockIdx.x * 4 + wv;

  const float* xr = x + (size_t)t * HD + lane * 16;
  float4 x0 = ((const float4*)xr)[0];
  float4 x1 = ((const float4*)xr)[1];
  float4 x2 = ((const float4*)xr)[2];
  float4 x3 = ((const float4*)xr)[3];

  // write bf16 copy of x (16 elements per lane, two 16B stores)
  unsigned short* xo = xbf + (size_t)t * HD + lane * 16;
  union { unsigned short us[8]; uint4 v; } pk;
  pk.us[0] = f2bf(x0.x); pk.us[1] = f2bf(x0.y); pk.us[2] = f2bf(x0.z); pk.us[3] = f2bf(x0.w);
  pk.us[4] = f2bf(x1.x); pk.us[5] = f2bf(x1.y); pk.us[6] = f2bf(x1.z); pk.us[7] = f2bf(x1.w);
  ((uint4*)xo)[0] = pk.v;
  pk.us[0] = f2bf(x2.x); pk.us[1] = f2bf(x2.y); pk.us[2] = f2bf(x2.z); pk.us[3] = f2bf(x2.w);
  pk.us[4] = f2bf(x3.x); pk.us[5] = f2bf(x3.y); pk.us[6] = f2bf(x3.z); pk.us[7] = f2bf(x3.w);
  ((uint4*)xo)[1] = pk.v;

  float lg[8];
#pragma unroll
  for (int e = 0; e < 8; ++e) {
    const float4* wr = (const float4*)(Wg + (size_t)e * HD + lane * 16);
    float4 a = wr[0], b = wr[1], c = wr[2], d = wr[3];
    lg[e] = a.x * x0.x + a.y * x0.y + a.z * x0.z + a.w * x0.w +
            b.x * x1.x + b.y * x1.y + b.z * x1.z + b.w * x1.w +
            c.x * x2.x + c.y * x2.y + c.z * x2.z + c.w * x2.w +
            d.x * x3.x + d.y * x3.y + d.z * x3.z + d.w * x3.w;
  }
#pragma unroll
  for (int off = 32; off > 0; off >>= 1) {
#pragma unroll
    for (int e = 0; e < 8; ++e) lg[e] += __shfl_xor(lg[e], off, 64);
  }

  if (lane == 0) {
    int i1 = 0; float m1 = lg[0];
#pragma unroll
    for (int e = 1; e < 8; ++e) { if (lg[e] > m1) { m1 = lg[e]; i1 = e; } }
    int i2 = -1; float m2 = -3.4e38f;
#pragma unroll
    for (int e = 0; e < 8; ++e) { if (e != i1 && lg[e] > m2) { m2 = lg[e]; i2 = e; } }
    float Z = 0.f;
#pragma unroll
    for (int e = 0; e < 8; ++e) Z += expf(lg[e] - m1);
    float s1 = 1.f / Z;                 // exp(0)/Z
    float s2 = expf(m2 - m1) / Z;
    float dn = s1 + s2 + 1e-20f;
    float w1 = s1 / dn, w2 = s2 / dn;
#pragma unroll
    for (int e = 0; e < 8; ++e) {
      float v = 0.f;
      if (e == i1) v = w1;
      if (e == i2) v = w2;
      wgt[(size_t)t * 8 + e] = v;
    }
  }
}

// ---------------- GEMM: C = A[M,K](bf16) * Bt[N,K](bf16)^T, 128x128 tile, BK=32 ----------------
// MODE 0: fc1  -> epilogue bias+relu+w-scale, store bf16 Hcat[T,NC1]
// MODE 1: fc2  -> epilogue + bs2 + sum_e w*b2, store fp32 out[T,HD]
template <int MODE>
__global__ __launch_bounds__(256) void moe_gemm(const unsigned short* __restrict__ A,
                                                const unsigned short* __restrict__ Bt,
                                                const float* __restrict__ wgt,
                                                const float* __restrict__ bias1,
                                                const float* __restrict__ b2,
                                                const float* __restrict__ bs2,
                                                unsigned short* __restrict__ outH,
                                                float* __restrict__ outY,
                                                int K) {
  __shared__ __align__(16) unsigned short As[128 * 32];
  __shared__ __align__(16) unsigned short Bs[128 * 32];

  const int tid   = threadIdx.x;
  const int lane  = tid & 63;
  const int wv    = tid >> 6;
  const int wm    = wv >> 1;
  const int wn    = wv & 1;
  const int tileM = blockIdx.y * 128;
  const int tileN = blockIdx.x * 128;
  const int r16   = lane & 15;
  const int quad  = lane >> 4;

  // staging: idx = i*256+tid ; LDS slot (row=idx>>2, chunk=idx&3) holds global chunk (chunk^(row&3))
  const unsigned short* gA[2];
  const unsigned short* gB[2];
  unsigned short* lA[2];
  unsigned short* lB[2];
#pragma unroll
  for (int i = 0; i < 2; ++i) {
    int idx = i * 256 + tid;
    int row = idx >> 2;
    int kc  = idx & 3;
    int kcg = kc ^ (row & 3);
    gA[i] = A + (size_t)(tileM + row) * K + kcg * 8;
    gB[i] = Bt + (size_t)(tileN + row) * K + kcg * 8;
    lA[i] = As + idx * 8;
    lB[i] = Bs + idx * 8;
  }

  // fragment LDS element offsets (16B ds_read_b128 each), inverse of the XOR swizzle
  int aoff[4], boff[4];
#pragma unroll
  for (int i = 0; i < 4; ++i) {
    int ra = wm * 64 + i * 16 + r16;
    aoff[i] = ra * 32 + ((quad ^ (ra & 3)) << 3);
    int rb = wn * 64 + i * 16 + r16;
    boff[i] = rb * 32 + ((quad ^ (rb & 3)) << 3);
  }

  f32x4 acc[4][4];
#pragma unroll
  for (int i = 0; i < 4; ++i)
#pragma unroll
    for (int j = 0; j < 4; ++j) acc[i][j] = (f32x4){0.f, 0.f, 0.f, 0.f};

  const int nkt = K >> 5;
  for (int kt = 0; kt < nkt; ++kt) {
    const int ko = kt << 5;
    gl2lds16(gA[0] + ko, lA[0]);
    gl2lds16(gA[1] + ko, lA[1]);
    gl2lds16(gB[0] + ko, lB[0]);
    gl2lds16(gB[1] + ko, lB[1]);
    __syncthreads();   // compiler drains vmcnt before s_barrier

    bf16x8 av[4], bv[4];
#pragma unroll
    for (int i = 0; i < 4; ++i) av[i] = *(const bf16x8*)(As + aoff[i]);
#pragma unroll
    for (int j = 0; j < 4; ++j) bv[j] = *(const bf16x8*)(Bs + boff[j]);
#pragma unroll
    for (int i = 0; i < 4; ++i)
#pragma unroll
      for (int j = 0; j < 4; ++j)
        acc[i][j] = __builtin_amdgcn_mfma_f32_16x16x32_bf16(av[i], bv[j], acc[i][j], 0, 0, 0);
    __syncthreads();
  }

  // epilogue. C/D layout: row=(lane>>4)*4+reg, col=lane&15
  if (MODE == 0) {
    float* wl = (float*)As;                 // 128 floats: w[tileM+r, e_block]
    const bool routed = (tileN < 1024);
    if (routed && tid < 128) wl[tid] = wgt[(size_t)(tileM + tid) * 8 + (tileN >> 7)];
    __syncthreads();
#pragma unroll
    for (int j = 0; j < 4; ++j) {
      const int col = tileN + wn * 64 + j * 16 + r16;
      const float bz = bias1[col];
#pragma unroll
      for (int i = 0; i < 4; ++i) {
#pragma unroll
        for (int r = 0; r < 4; ++r) {
          const int lrow = wm * 64 + i * 16 + quad * 4 + r;
          float v = acc[i][j][r] + bz;
          v = fmaxf(v, 0.f);
          if (routed) v *= wl[lrow];
          outH[(size_t)(tileM + lrow) * NC1 + col] = f2bf(v);
        }
      }
    }
  } else {
    float* wl = (float*)As;                 // [128][8] w tile
    for (int idx = tid; idx < 128 * 8; idx += 256) wl[idx] = wgt[(size_t)tileM * 8 + idx];
    __syncthreads();
    float b2c[4][8], bsc[4];
#pragma unroll
    for (int j = 0; j < 4; ++j) {
      const int col = tileN + wn * 64 + j * 16 + r16;
      bsc[j] = bs2[col];
#pragma unroll
      for (int e = 0; e < 8; ++e) b2c[j][e] = b2[(size_t)e * HD + col];
    }
#pragma unroll
    for (int i = 0; i < 4; ++i) {
#pragma unroll
      for (int r = 0; r < 4; ++r) {
        const int lrow = wm * 64 + i * 16 + quad * 4 + r;
        float w8[8];
#pragma unroll
        for (int e = 0; e < 8; ++e) w8[e] = wl[lrow * 8 + e];
#pragma unroll
        for (int j = 0; j < 4; ++j) {
          const int col = tileN + wn * 64 + j * 16 + r16;
          float v = acc[i][j][r] + bsc[j];
#pragma unroll
          for (int e = 0; e < 8; ++e) v += w8[e] * b2c[j][e];
          outY[(size_t)(tileM + lrow) * HD + col] = v;
        }
      }
    }
  }
}

extern "C" void kernel_launch(void* const* d_in, const int* in_sizes, int n_in,
                              void* d_out, int out_size, void* d_ws, size_t ws_size,
                              hipStream_t stream) {
  const float* x   = (const float*)d_in[0];
  const float* Wg  = (const float*)d_in[1];
  const float* W1  = (const float*)d_in[2];
  const float* b1  = (const float*)d_in[3];
  const float* W2  = (const float*)d_in[4];
  const float* b2  = (const float*)d_in[5];
  const float* Ws1 = (const float*)d_in[6];
  const float* bs1 = (const float*)d_in[7];
  const float* Ws2 = (const float*)d_in[8];
  const float* bs2 = (const float*)d_in[9];

  char* ws = (char*)d_ws;
  size_t off = 0;
  unsigned short* xbf   = (unsigned short*)(ws + off); off += (size_t)TTOK * HD * 2;   // 32 MiB
  unsigned short* Hcat  = (unsigned short*)(ws + off); off += (size_t)TTOK * NC1 * 2;  // 48 MiB
  unsigned short* W1cat = (unsigned short*)(ws + off); off += (size_t)NC1 * HD * 2;
  unsigned short* W2cat = (unsigned short*)(ws + off); off += (size_t)HD * KC2 * 2;
  float* wgt            = (float*)(ws + off);          off += (size_t)TTOK * 8 * 4;
  float* bias1          = (float*)(ws + off);          off += (size_t)NC1 * 4;

  prep_kernel<<<12295, 256, 0, stream>>>(W1, Ws1, W2, Ws2, b1, bs1, W1cat, W2cat, bias1);
  gate_kernel<<<TTOK / 4, 256, 0, stream>>>(x, Wg, xbf, wgt);
  moe_gemm<0><<<dim3(NC1 / 128, TTOK / 128), 256, 0, stream>>>(
      xbf, W1cat, wgt, bias1, nullptr, nullptr, Hcat, nullptr, HD);
  moe_gemm<1><<<dim3(HD / 128, TTOK / 128), 256, 0, stream>>>(
      Hcat, W2cat, wgt, nullptr, b2, bs2, nullptr, (float*)d_out, KC2);
}

// Round 2
// 329.342 us; speedup vs baseline: 1.0404x; 1.0404x over previous
//
#include <hip/hip_runtime.h>
#include <cstdint>

#define TTOK 16384
#define HD   1024
#define NE   8
#define NDE  128
#define NDS  512
#define NC1  1536   // fc1 output cols = E*DE + DS
#define KC2  1536   // fc2 K

typedef float  f32x4  __attribute__((ext_vector_type(4)));
typedef __bf16 bf16x8 __attribute__((ext_vector_type(8)));

__device__ __forceinline__ unsigned short f2bf(float f) {
  unsigned int u = __float_as_uint(f);
  u += 0x7fffu + ((u >> 16) & 1u);   // RNE; inputs finite
  return (unsigned short)(u >> 16);
}

__device__ __forceinline__ void gl2lds16(const void* gp, void* lp) {
  void* g0 = const_cast<void*>(gp);
  __builtin_amdgcn_global_load_lds((__attribute__((address_space(1))) void*)g0,
                                   (__attribute__((address_space(3))) void*)lp,
                                   16, 0, 0);
}

// ---------------- prep: pack weights into bf16 concatenated layouts ----------------
__global__ void prep_kernel(const float* __restrict__ W1, const float* __restrict__ Ws1,
                            const float* __restrict__ W2, const float* __restrict__ Ws2,
                            const float* __restrict__ b1, const float* __restrict__ bs1,
                            unsigned short* __restrict__ W1cat,
                            unsigned short* __restrict__ W2cat,
                            float* __restrict__ bias1) {
  const int total = NC1 * HD + HD * KC2 + NC1;
  for (int idx = blockIdx.x * 256 + threadIdx.x; idx < total; idx += gridDim.x * 256) {
    if (idx < NC1 * HD) {
      int r = idx >> 10, k = idx & 1023;
      float v = (r < 1024) ? W1[idx] : Ws1[(size_t)(r - 1024) * HD + k];
      W1cat[idx] = f2bf(v);
    } else if (idx < NC1 * HD + HD * KC2) {
      int i2 = idx - NC1 * HD;
      int h = i2 / KC2;
      int j = i2 - h * KC2;
      float v = (j < 1024) ? W2[(size_t)((j >> 7) * HD + h) * NDE + (j & 127)]
                           : Ws2[(size_t)h * NDS + (j - 1024)];
      W2cat[i2] = f2bf(v);
    } else {
      int r = idx - (NC1 * HD + HD * KC2);
      bias1[r] = (r < 1024) ? b1[r] : bs1[r - 1024];
    }
  }
}

// ---------------- gate: logits fp32, softmax, top-2, w[T,8]; also x -> bf16 ----------------
__global__ __launch_bounds__(256) void gate_kernel(const float* __restrict__ x,
                                                   const float* __restrict__ Wg,
                                                   unsigned short* __restrict__ xbf,
                                                   float* __restrict__ wgt) {
  const int lane = threadIdx.x & 63;
  const int wv   = threadIdx.x >> 6;
  const int t    = blockIdx.x * 4 + wv;

  const float* xr = x + (size_t)t * HD + lane * 16;
  float4 x0 = ((const float4*)xr)[0];
  float4 x1 = ((const float4*)xr)[1];
  float4 x2 = ((const float4*)xr)[2];
  float4 x3 = ((const float4*)xr)[3];

  unsigned short* xo = xbf + (size_t)t * HD + lane * 16;
  union { unsigned short us[8]; uint4 v; } pk;
  pk.us[0] = f2bf(x0.x); pk.us[1] = f2bf(x0.y); pk.us[2] = f2bf(x0.z); pk.us[3] = f2bf(x0.w);
  pk.us[4] = f2bf(x1.x); pk.us[5] = f2bf(x1.y); pk.us[6] = f2bf(x1.z); pk.us[7] = f2bf(x1.w);
  ((uint4*)xo)[0] = pk.v;
  pk.us[0] = f2bf(x2.x); pk.us[1] = f2bf(x2.y); pk.us[2] = f2bf(x2.z); pk.us[3] = f2bf(x2.w);
  pk.us[4] = f2bf(x3.x); pk.us[5] = f2bf(x3.y); pk.us[6] = f2bf(x3.z); pk.us[7] = f2bf(x3.w);
  ((uint4*)xo)[1] = pk.v;

  float lg[8];
#pragma unroll
  for (int e = 0; e < 8; ++e) {
    const float4* wr = (const float4*)(Wg + (size_t)e * HD + lane * 16);
    float4 a = wr[0], b = wr[1], c = wr[2], d = wr[3];
    lg[e] = a.x * x0.x + a.y * x0.y + a.z * x0.z + a.w * x0.w +
            b.x * x1.x + b.y * x1.y + b.z * x1.z + b.w * x1.w +
            c.x * x2.x + c.y * x2.y + c.z * x2.z + c.w * x2.w +
            d.x * x3.x + d.y * x3.y + d.z * x3.z + d.w * x3.w;
  }
#pragma unroll
  for (int off = 32; off > 0; off >>= 1) {
#pragma unroll
    for (int e = 0; e < 8; ++e) lg[e] += __shfl_xor(lg[e], off, 64);
  }

  if (lane == 0) {
    int i1 = 0; float m1 = lg[0];
#pragma unroll
    for (int e = 1; e < 8; ++e) { if (lg[e] > m1) { m1 = lg[e]; i1 = e; } }
    int i2 = -1; float m2 = -3.4e38f;
#pragma unroll
    for (int e = 0; e < 8; ++e) { if (e != i1 && lg[e] > m2) { m2 = lg[e]; i2 = e; } }
    float Z = 0.f;
#pragma unroll
    for (int e = 0; e < 8; ++e) Z += expf(lg[e] - m1);
    float s1 = 1.f / Z;
    float s2 = expf(m2 - m1) / Z;
    float dn = s1 + s2 + 1e-20f;
    float w1 = s1 / dn, w2 = s2 / dn;
#pragma unroll
    for (int e = 0; e < 8; ++e) {
      float v = 0.f;
      if (e == i1) v = w1;
      if (e == i2) v = w2;
      wgt[(size_t)t * 8 + e] = v;
    }
  }
}

// ---------------- GEMM: C = A[M,K](bf16) * Bt[N,K](bf16)^T, 128x128 tile, BK=32 ----------------
// 1-D grid, XCD-aligned remap: L = xcd + 8*slot; per XCD, slots iterate n-tiles
// innermost over m-tiles with m%8==xcd. All n-tiles of an m-tile share an XCD
// (true for both round-robin and chunked XCD mappings since L,L+8 co-locate),
// so each A-row is fetched into exactly one L2 and reused NTN times.
// MODE 0: fc1 -> bias+relu+w-scale, store bf16 Hcat[T,NC1]
// MODE 1: fc2 -> + bs2 + sum_e w*b2, store fp32 out[T,HD]
template <int MODE, int NTN>
__global__ __launch_bounds__(256) void moe_gemm(const unsigned short* __restrict__ A,
                                                const unsigned short* __restrict__ Bt,
                                                const float* __restrict__ wgt,
                                                const float* __restrict__ bias1,
                                                const float* __restrict__ b2,
                                                const float* __restrict__ bs2,
                                                unsigned short* __restrict__ outH,
                                                float* __restrict__ outY,
                                                int K) {
  __shared__ __align__(16) unsigned short As[128 * 32];
  __shared__ __align__(16) unsigned short Bs[128 * 32];

  const int tid   = threadIdx.x;
  const int lane  = tid & 63;
  const int wv    = tid >> 6;
  const int wm    = wv >> 1;
  const int wn    = wv & 1;
  const int r16   = lane & 15;
  const int quad  = lane >> 4;

  // XCD-aligned (m,n) decode
  const int L    = blockIdx.x;
  const int xcd  = L & 7;
  const int slot = L >> 3;           // [0, 16*NTN)
  const int mg   = slot / NTN;       // [0, 16)
  const int nn   = slot - mg * NTN;  // [0, NTN)
  const int tileM = (xcd + (mg << 3)) << 7;
  const int tileN = nn << 7;

  const unsigned short* gA[2];
  const unsigned short* gB[2];
  unsigned short* lA[2];
  unsigned short* lB[2];
#pragma unroll
  for (int i = 0; i < 2; ++i) {
    int idx = i * 256 + tid;
    int row = idx >> 2;
    int kc  = idx & 3;
    int kcg = kc ^ (row & 3);
    gA[i] = A + (size_t)(tileM + row) * K + kcg * 8;
    gB[i] = Bt + (size_t)(tileN + row) * K + kcg * 8;
    lA[i] = As + idx * 8;
    lB[i] = Bs + idx * 8;
  }

  int aoff[4], boff[4];
#pragma unroll
  for (int i = 0; i < 4; ++i) {
    int ra = wm * 64 + i * 16 + r16;
    aoff[i] = ra * 32 + ((quad ^ (ra & 3)) << 3);
    int rb = wn * 64 + i * 16 + r16;
    boff[i] = rb * 32 + ((quad ^ (rb & 3)) << 3);
  }

  f32x4 acc[4][4];
#pragma unroll
  for (int i = 0; i < 4; ++i)
#pragma unroll
    for (int j = 0; j < 4; ++j) acc[i][j] = (f32x4){0.f, 0.f, 0.f, 0.f};

  const int nkt = K >> 5;
  for (int kt = 0; kt < nkt; ++kt) {
    const int ko = kt << 5;
    gl2lds16(gA[0] + ko, lA[0]);
    gl2lds16(gA[1] + ko, lA[1]);
    gl2lds16(gB[0] + ko, lB[0]);
    gl2lds16(gB[1] + ko, lB[1]);
    __syncthreads();

    bf16x8 av[4], bv[4];
#pragma unroll
    for (int i = 0; i < 4; ++i) av[i] = *(const bf16x8*)(As + aoff[i]);
#pragma unroll
    for (int j = 0; j < 4; ++j) bv[j] = *(const bf16x8*)(Bs + boff[j]);
#pragma unroll
    for (int i = 0; i < 4; ++i)
#pragma unroll
      for (int j = 0; j < 4; ++j)
        acc[i][j] = __builtin_amdgcn_mfma_f32_16x16x32_bf16(av[i], bv[j], acc[i][j], 0, 0, 0);
    __syncthreads();
  }

  // epilogue. C/D layout: row=(lane>>4)*4+reg, col=lane&15
  if (MODE == 0) {
    float* wl = (float*)As;                 // 128 floats: w[tileM+r, e_block]
    const bool routed = (tileN < 1024);
    if (routed && tid < 128) wl[tid] = wgt[(size_t)(tileM + tid) * 8 + (tileN >> 7)];
    __syncthreads();
#pragma unroll
    for (int j = 0; j < 4; ++j) {
      const int col = tileN + wn * 64 + j * 16 + r16;
      const float bz = bias1[col];
#pragma unroll
      for (int i = 0; i < 4; ++i) {
#pragma unroll
        for (int r = 0; r < 4; ++r) {
          const int lrow = wm * 64 + i * 16 + quad * 4 + r;
          float v = acc[i][j][r] + bz;
          v = fmaxf(v, 0.f);
          if (routed) v *= wl[lrow];
          outH[(size_t)(tileM + lrow) * NC1 + col] = f2bf(v);
        }
      }
    }
  } else {
    float* wl = (float*)As;                 // [128][9] padded w tile (bank-conflict fix)
    for (int idx = tid; idx < 128 * 8; idx += 256) {
      int rr = idx >> 3, ee = idx & 7;
      wl[rr * 9 + ee] = wgt[(size_t)tileM * 8 + idx];
    }
    __syncthreads();
    float b2c[4][8], bsc[4];
#pragma unroll
    for (int j = 0; j < 4; ++j) {
      const int col = tileN + wn * 64 + j * 16 + r16;
      bsc[j] = bs2[col];
#pragma unroll
      for (int e = 0; e < 8; ++e) b2c[j][e] = b2[(size_t)e * HD + col];
    }
#pragma unroll
    for (int i = 0; i < 4; ++i) {
#pragma unroll
      for (int r = 0; r < 4; ++r) {
        const int lrow = wm * 64 + i * 16 + quad * 4 + r;
        float w8[8];
#pragma unroll
        for (int e = 0; e < 8; ++e) w8[e] = wl[lrow * 9 + e];
#pragma unroll
        for (int j = 0; j < 4; ++j) {
          const int col = tileN + wn * 64 + j * 16 + r16;
          float v = acc[i][j][r] + bsc[j];
#pragma unroll
          for (int e = 0; e < 8; ++e) v += w8[e] * b2c[j][e];
          outY[(size_t)(tileM + lrow) * HD + col] = v;
        }
      }
    }
  }
}

extern "C" void kernel_launch(void* const* d_in, const int* in_sizes, int n_in,
                              void* d_out, int out_size, void* d_ws, size_t ws_size,
                              hipStream_t stream) {
  const float* x   = (const float*)d_in[0];
  const float* Wg  = (const float*)d_in[1];
  const float* W1  = (const float*)d_in[2];
  const float* b1  = (const float*)d_in[3];
  const float* W2  = (const float*)d_in[4];
  const float* b2  = (const float*)d_in[5];
  const float* Ws1 = (const float*)d_in[6];
  const float* bs1 = (const float*)d_in[7];
  const float* Ws2 = (const float*)d_in[8];
  const float* bs2 = (const float*)d_in[9];

  char* ws = (char*)d_ws;
  size_t off = 0;
  unsigned short* xbf   = (unsigned short*)(ws + off); off += (size_t)TTOK * HD * 2;   // 32 MiB
  unsigned short* Hcat  = (unsigned short*)(ws + off); off += (size_t)TTOK * NC1 * 2;  // 48 MiB
  unsigned short* W1cat = (unsigned short*)(ws + off); off += (size_t)NC1 * HD * 2;
  unsigned short* W2cat = (unsigned short*)(ws + off); off += (size_t)HD * KC2 * 2;
  float* wgt            = (float*)(ws + off);          off += (size_t)TTOK * 8 * 4;
  float* bias1          = (float*)(ws + off);          off += (size_t)NC1 * 4;

  prep_kernel<<<3080, 256, 0, stream>>>(W1, Ws1, W2, Ws2, b1, bs1, W1cat, W2cat, bias1);
  gate_kernel<<<TTOK / 4, 256, 0, stream>>>(x, Wg, xbf, wgt);
  moe_gemm<0, NC1 / 128><<<NC1 / 128 * TTOK / 128, 256, 0, stream>>>(
      xbf, W1cat, wgt, bias1, nullptr, nullptr, Hcat, nullptr, HD);
  moe_gemm<1, HD / 128><<<HD / 128 * TTOK / 128, 256, 0, stream>>>(
      Hcat, W2cat, wgt, nullptr, b2, bs2, nullptr, (float*)d_out, KC2);
}

// Round 3
// 304.568 us; speedup vs baseline: 1.1251x; 1.0813x over previous
//
#include <hip/hip_runtime.h>
#include <cstdint>

#define TTOK 16384
#define HD   1024
#define NE   8
#define NDE  128
#define NDS  512
#define NC1  1536   // fc1 output cols = E*DE + DS
#define KC2  1536   // fc2 K

typedef float  f32x4  __attribute__((ext_vector_type(4)));
typedef __bf16 bf16x8 __attribute__((ext_vector_type(8)));

__device__ __forceinline__ unsigned short f2bf(float f) {
  unsigned int u = __float_as_uint(f);
  u += 0x7fffu + ((u >> 16) & 1u);   // RNE; inputs finite
  return (unsigned short)(u >> 16);
}

__device__ __forceinline__ void gl2lds16(const void* gp, void* lp) {
  void* g0 = const_cast<void*>(gp);
  __builtin_amdgcn_global_load_lds((__attribute__((address_space(1))) void*)g0,
                                   (__attribute__((address_space(3))) void*)lp,
                                   16, 0, 0);
}

// ---------------- prep: pack weights into bf16 concatenated layouts ----------------
__global__ void prep_kernel(const float* __restrict__ W1, const float* __restrict__ Ws1,
                            const float* __restrict__ W2, const float* __restrict__ Ws2,
                            const float* __restrict__ b1, const float* __restrict__ bs1,
                            unsigned short* __restrict__ W1cat,
                            unsigned short* __restrict__ W2cat,
                            float* __restrict__ bias1) {
  const int total = NC1 * HD + HD * KC2 + NC1;
  for (int idx = blockIdx.x * 256 + threadIdx.x; idx < total; idx += gridDim.x * 256) {
    if (idx < NC1 * HD) {
      int r = idx >> 10, k = idx & 1023;
      float v = (r < 1024) ? W1[idx] : Ws1[(size_t)(r - 1024) * HD + k];
      W1cat[idx] = f2bf(v);
    } else if (idx < NC1 * HD + HD * KC2) {
      int i2 = idx - NC1 * HD;
      int h = i2 / KC2;
      int j = i2 - h * KC2;
      float v = (j < 1024) ? W2[(size_t)((j >> 7) * HD + h) * NDE + (j & 127)]
                           : Ws2[(size_t)h * NDS + (j - 1024)];
      W2cat[i2] = f2bf(v);
    } else {
      int r = idx - (NC1 * HD + HD * KC2);
      bias1[r] = (r < 1024) ? b1[r] : bs1[r - 1024];
    }
  }
}

// ---------------- gate: logits fp32, softmax, top-2, w[T,8]; also x -> bf16 ----------------
__global__ __launch_bounds__(256) void gate_kernel(const float* __restrict__ x,
                                                   const float* __restrict__ Wg,
                                                   unsigned short* __restrict__ xbf,
                                                   float* __restrict__ wgt) {
  const int lane = threadIdx.x & 63;
  const int wv   = threadIdx.x >> 6;
  const int t    = blockIdx.x * 4 + wv;

  const float* xr = x + (size_t)t * HD + lane * 16;
  float4 x0 = ((const float4*)xr)[0];
  float4 x1 = ((const float4*)xr)[1];
  float4 x2 = ((const float4*)xr)[2];
  float4 x3 = ((const float4*)xr)[3];

  unsigned short* xo = xbf + (size_t)t * HD + lane * 16;
  union { unsigned short us[8]; uint4 v; } pk;
  pk.us[0] = f2bf(x0.x); pk.us[1] = f2bf(x0.y); pk.us[2] = f2bf(x0.z); pk.us[3] = f2bf(x0.w);
  pk.us[4] = f2bf(x1.x); pk.us[5] = f2bf(x1.y); pk.us[6] = f2bf(x1.z); pk.us[7] = f2bf(x1.w);
  ((uint4*)xo)[0] = pk.v;
  pk.us[0] = f2bf(x2.x); pk.us[1] = f2bf(x2.y); pk.us[2] = f2bf(x2.z); pk.us[3] = f2bf(x2.w);
  pk.us[4] = f2bf(x3.x); pk.us[5] = f2bf(x3.y); pk.us[6] = f2bf(x3.z); pk.us[7] = f2bf(x3.w);
  ((uint4*)xo)[1] = pk.v;

  float lg[8];
#pragma unroll
  for (int e = 0; e < 8; ++e) {
    const float4* wr = (const float4*)(Wg + (size_t)e * HD + lane * 16);
    float4 a = wr[0], b = wr[1], c = wr[2], d = wr[3];
    lg[e] = a.x * x0.x + a.y * x0.y + a.z * x0.z + a.w * x0.w +
            b.x * x1.x + b.y * x1.y + b.z * x1.z + b.w * x1.w +
            c.x * x2.x + c.y * x2.y + c.z * x2.z + c.w * x2.w +
            d.x * x3.x + d.y * x3.y + d.z * x3.z + d.w * x3.w;
  }
#pragma unroll
  for (int off = 32; off > 0; off >>= 1) {
#pragma unroll
    for (int e = 0; e < 8; ++e) lg[e] += __shfl_xor(lg[e], off, 64);
  }

  if (lane == 0) {
    int i1 = 0; float m1 = lg[0];
#pragma unroll
    for (int e = 1; e < 8; ++e) { if (lg[e] > m1) { m1 = lg[e]; i1 = e; } }
    int i2 = -1; float m2 = -3.4e38f;
#pragma unroll
    for (int e = 0; e < 8; ++e) { if (e != i1 && lg[e] > m2) { m2 = lg[e]; i2 = e; } }
    float Z = 0.f;
#pragma unroll
    for (int e = 0; e < 8; ++e) Z += expf(lg[e] - m1);
    float s1 = 1.f / Z;
    float s2 = expf(m2 - m1) / Z;
    float dn = s1 + s2 + 1e-20f;
    float w1 = s1 / dn, w2 = s2 / dn;
#pragma unroll
    for (int e = 0; e < 8; ++e) {
      float v = 0.f;
      if (e == i1) v = w1;
      if (e == i2) v = w2;
      wgt[(size_t)t * 8 + e] = v;
    }
  }
}

// ---------------- GEMM: C = A[M,K](bf16) * Bt[N,K](bf16)^T, 128x128 tile, BK=64 ----------------
// 1-D grid, XCD-aligned remap (all n-tiles of an m-tile on one XCD).
// LDS row = 64 elems = 128 B = all 32 banks. Swizzle: 16B chunk c of row r stored
// at slot c^(r&7). Fragment read (k-group g, quad q) wants chunk g*4+q ->
// slot (q^(r&7))^(g<<2); per ds_read_b128 each consecutive-8-lane group covers
// all 8 slot-groups once -> conflict-free.
// MODE 0: fc1 -> bias+relu+w-scale, store bf16 Hcat[T,NC1]
// MODE 1: fc2 -> + bs2 + sum_e w*b2, store fp32 out[T,HD]
template <int MODE, int NTN>
__global__ __launch_bounds__(256) void moe_gemm(const unsigned short* __restrict__ A,
                                                const unsigned short* __restrict__ Bt,
                                                const float* __restrict__ wgt,
                                                const float* __restrict__ bias1,
                                                const float* __restrict__ b2,
                                                const float* __restrict__ bs2,
                                                unsigned short* __restrict__ outH,
                                                float* __restrict__ outY,
                                                int K) {
  __shared__ __align__(16) unsigned short As[128 * 64];
  __shared__ __align__(16) unsigned short Bs[128 * 64];

  const int tid   = threadIdx.x;
  const int lane  = tid & 63;
  const int wv    = tid >> 6;
  const int wm    = wv >> 1;
  const int wn    = wv & 1;
  const int r16   = lane & 15;
  const int quad  = lane >> 4;

  // XCD-aligned (m,n) decode
  const int L    = blockIdx.x;
  const int xcd  = L & 7;
  const int slot = L >> 3;
  const int mg   = slot / NTN;
  const int nn   = slot - mg * NTN;
  const int tileM = (xcd + (mg << 3)) << 7;
  const int tileN = nn << 7;

  // staging: idx = i*256+tid ; row = idx>>3, slot c = idx&7 holds global chunk c^(row&7)
  const unsigned short* gA[4];
  const unsigned short* gB[4];
  unsigned short* lA[4];
  unsigned short* lB[4];
#pragma unroll
  for (int i = 0; i < 4; ++i) {
    int idx = i * 256 + tid;
    int row = idx >> 3;
    int c   = idx & 7;
    int gcg = c ^ (row & 7);
    gA[i] = A + (size_t)(tileM + row) * K + gcg * 8;
    gB[i] = Bt + (size_t)(tileN + row) * K + gcg * 8;
    lA[i] = As + idx * 8;
    lB[i] = Bs + idx * 8;
  }

  // fragment offsets for k-group g=0; g=1 is offset^32 (slot bit2 flip)
  int aoff[4], boff[4];
#pragma unroll
  for (int i = 0; i < 4; ++i) {
    int ra = wm * 64 + i * 16 + r16;
    aoff[i] = ra * 64 + ((quad ^ (ra & 7)) << 3);
    int rb = wn * 64 + i * 16 + r16;
    boff[i] = rb * 64 + ((quad ^ (rb & 7)) << 3);
  }

  f32x4 acc[4][4];
#pragma unroll
  for (int i = 0; i < 4; ++i)
#pragma unroll
    for (int j = 0; j < 4; ++j) acc[i][j] = (f32x4){0.f, 0.f, 0.f, 0.f};

  const int nkt = K >> 6;
  for (int kt = 0; kt < nkt; ++kt) {
    const int ko = kt << 6;
#pragma unroll
    for (int i = 0; i < 4; ++i) gl2lds16(gA[i] + ko, lA[i]);
#pragma unroll
    for (int i = 0; i < 4; ++i) gl2lds16(gB[i] + ko, lB[i]);
    __syncthreads();

#pragma unroll
    for (int g = 0; g < 2; ++g) {
      const int gx = g << 5;
      bf16x8 av[4], bv[4];
#pragma unroll
      for (int i = 0; i < 4; ++i) av[i] = *(const bf16x8*)(As + (aoff[i] ^ gx));
#pragma unroll
      for (int j = 0; j < 4; ++j) bv[j] = *(const bf16x8*)(Bs + (boff[j] ^ gx));
#pragma unroll
      for (int i = 0; i < 4; ++i)
#pragma unroll
        for (int j = 0; j < 4; ++j)
          acc[i][j] = __builtin_amdgcn_mfma_f32_16x16x32_bf16(av[i], bv[j], acc[i][j], 0, 0, 0);
    }
    __syncthreads();
  }

  // epilogue. C/D layout: row=(lane>>4)*4+reg, col=lane&15
  if (MODE == 0) {
    float* wl = (float*)As;                 // 128 floats: w[tileM+r, e_block]
    const bool routed = (tileN < 1024);
    if (routed && tid < 128) wl[tid] = wgt[(size_t)(tileM + tid) * 8 + (tileN >> 7)];
    __syncthreads();
#pragma unroll
    for (int j = 0; j < 4; ++j) {
      const int col = tileN + wn * 64 + j * 16 + r16;
      const float bz = bias1[col];
#pragma unroll
      for (int i = 0; i < 4; ++i) {
#pragma unroll
        for (int r = 0; r < 4; ++r) {
          const int lrow = wm * 64 + i * 16 + quad * 4 + r;
          float v = acc[i][j][r] + bz;
          v = fmaxf(v, 0.f);
          if (routed) v *= wl[lrow];
          outH[(size_t)(tileM + lrow) * NC1 + col] = f2bf(v);
        }
      }
    }
  } else {
    float* wl = (float*)As;                 // [128][9] padded w tile
    for (int idx = tid; idx < 128 * 8; idx += 256) {
      int rr = idx >> 3, ee = idx & 7;
      wl[rr * 9 + ee] = wgt[(size_t)tileM * 8 + idx];
    }
    __syncthreads();
    float b2c[4][8], bsc[4];
#pragma unroll
    for (int j = 0; j < 4; ++j) {
      const int col = tileN + wn * 64 + j * 16 + r16;
      bsc[j] = bs2[col];
#pragma unroll
      for (int e = 0; e < 8; ++e) b2c[j][e] = b2[(size_t)e * HD + col];
    }
#pragma unroll
    for (int i = 0; i < 4; ++i) {
#pragma unroll
      for (int r = 0; r < 4; ++r) {
        const int lrow = wm * 64 + i * 16 + quad * 4 + r;
        float w8[8];
#pragma unroll
        for (int e = 0; e < 8; ++e) w8[e] = wl[lrow * 9 + e];
#pragma unroll
        for (int j = 0; j < 4; ++j) {
          const int col = tileN + wn * 64 + j * 16 + r16;
          float v = acc[i][j][r] + bsc[j];
#pragma unroll
          for (int e = 0; e < 8; ++e) v += w8[e] * b2c[j][e];
          outY[(size_t)(tileM + lrow) * HD + col] = v;
        }
      }
    }
  }
}

extern "C" void kernel_launch(void* const* d_in, const int* in_sizes, int n_in,
                              void* d_out, int out_size, void* d_ws, size_t ws_size,
                              hipStream_t stream) {
  const float* x   = (const float*)d_in[0];
  const float* Wg  = (const float*)d_in[1];
  const float* W1  = (const float*)d_in[2];
  const float* b1  = (const float*)d_in[3];
  const float* W2  = (const float*)d_in[4];
  const float* b2  = (const float*)d_in[5];
  const float* Ws1 = (const float*)d_in[6];
  const float* bs1 = (const float*)d_in[7];
  const float* Ws2 = (const float*)d_in[8];
  const float* bs2 = (const float*)d_in[9];

  char* ws = (char*)d_ws;
  size_t off = 0;
  unsigned short* xbf   = (unsigned short*)(ws + off); off += (size_t)TTOK * HD * 2;   // 32 MiB
  unsigned short* Hcat  = (unsigned short*)(ws + off); off += (size_t)TTOK * NC1 * 2;  // 48 MiB
  unsigned short* W1cat = (unsigned short*)(ws + off); off += (size_t)NC1 * HD * 2;
  unsigned short* W2cat = (unsigned short*)(ws + off); off += (size_t)HD * KC2 * 2;
  float* wgt            = (float*)(ws + off);          off += (size_t)TTOK * 8 * 4;
  float* bias1          = (float*)(ws + off);          off += (size_t)NC1 * 4;

  prep_kernel<<<3080, 256, 0, stream>>>(W1, Ws1, W2, Ws2, b1, bs1, W1cat, W2cat, bias1);
  gate_kernel<<<TTOK / 4, 256, 0, stream>>>(x, Wg, xbf, wgt);
  moe_gemm<0, NC1 / 128><<<NC1 / 128 * TTOK / 128, 256, 0, stream>>>(
      xbf, W1cat, wgt, bias1, nullptr, nullptr, Hcat, nullptr, HD);
  moe_gemm<1, HD / 128><<<HD / 128 * TTOK / 128, 256, 0, stream>>>(
      Hcat, W2cat, wgt, nullptr, b2, bs2, nullptr, (float*)d_out, KC2);
}